// Round 6
// baseline (627.215 us; speedup 1.0000x reference)
//
#include <hip/hip_runtime.h>
#include <cstdint>
#include <cstddef>

#define NN 50000
#define EE 1600000
#define D  64
#define DE 16

typedef __attribute__((ext_vector_type(2))) float vf2;

__device__ __forceinline__ float bf2f(unsigned short u) {
    return __uint_as_float(((unsigned)u) << 16);
}
__device__ __forceinline__ unsigned short f2bf(float f) {
    unsigned u = __float_as_uint(f);
    unsigned r = u + 0x7FFFu + ((u >> 16) & 1u);   // RNE
    return (unsigned short)(r >> 16);
}

// ---------------- histogram of dst (4-edge ILP -> 4 atomic chains in flight)
#define HI_ILP 4
__global__ __launch_bounds__(256) void k_hist(const int* __restrict__ dst,
                                              int* __restrict__ counts) {
    int base = blockIdx.x * (256 * HI_ILP) + threadIdx.x;
    int dd[HI_ILP]; bool v[HI_ILP];
    #pragma unroll
    for (int j = 0; j < HI_ILP; j++) {
        int e = base + j * 256;
        v[j] = (e < EE);
        dd[j] = dst[v[j] ? e : 0];
    }
    #pragma unroll
    for (int j = 0; j < HI_ILP; j++)
        if (v[j]) atomicAdd(&counts[dd[j]], 1);
}

// ---------------- 3-kernel exclusive scan over counts (chunks of 256)
__global__ __launch_bounds__(256) void k_scanA(const int* counts, int* bsum) {
    __shared__ int tmp[256];
    int t = threadIdx.x, i = blockIdx.x * 256 + t;
    tmp[t] = (i < NN) ? counts[i] : 0;
    __syncthreads();
    for (int off = 128; off; off >>= 1) {
        if (t < off) tmp[t] += tmp[t + off];
        __syncthreads();
    }
    if (t == 0) bsum[blockIdx.x] = tmp[0];
}

__global__ __launch_bounds__(256) void k_scanB(int* bsum, int nchunks) {
    __shared__ int tmp[256];
    int t = threadIdx.x;
    int v = (t < nchunks) ? bsum[t] : 0;
    tmp[t] = v; __syncthreads();
    for (int off = 1; off < 256; off <<= 1) {
        int x = (t >= off) ? tmp[t - off] : 0;
        __syncthreads();
        tmp[t] += x;
        __syncthreads();
    }
    if (t < nchunks) bsum[t] = tmp[t] - v;   // exclusive
}

__global__ __launch_bounds__(256) void k_scanC(const int* counts, const int* bsumex,
                                               int* offsets, int* cursor) {
    __shared__ int tmp[256];
    int t = threadIdx.x, i = blockIdx.x * 256 + t;
    int v = (i < NN) ? counts[i] : 0;
    tmp[t] = v; __syncthreads();
    for (int off = 1; off < 256; off <<= 1) {
        int x = (t >= off) ? tmp[t - off] : 0;
        __syncthreads();
        tmp[t] += x;
        __syncthreads();
    }
    int excl = tmp[t] - v + bsumex[blockIdx.x];
    if (i < NN) { offsets[i] = excl; cursor[i] = excl; }
}

// ---------------- scatter edges into dst-sorted AoS records {src, eid, ee1, ee2}.
// R12: ee precomputed HERE again (R2 design) — keeping it out of gat pass 1 keeps
// the logit critical path to one 16B rec gather (R5's in-gat recompute put the
// 64B ea gather + 16 FMA on the wave-synchronous softmax path: gat 112->135us).
// ILP-8 phases: coalesced src/dst loads -> 8 atomic chains in flight -> per-edge
// coalesced ea read + dot + scattered 16B rec write.
#define SC_ILP 8
__global__ __launch_bounds__(256) void k_scatter(const int* __restrict__ src,
                                                 const int* __restrict__ dst,
                                                 const float* __restrict__ ea,
                                                 const float* __restrict__ We1,
                                                 const float* __restrict__ ae1,
                                                 const float* __restrict__ We2,
                                                 const float* __restrict__ ae2,
                                                 int* __restrict__ cursor,
                                                 int4* __restrict__ recs) {
    __shared__ float wsh[32];
    int t = threadIdx.x;
    if (t < 32) {
        const float* We = (t < 16) ? We1 : We2;
        const float* ae = (t < 16) ? ae1 : ae2;
        int k = t & 15;
        float acc = 0.f;
        #pragma unroll
        for (int c = 0; c < 64; c++) acc += We[k * 64 + c] * ae[c];
        wsh[t] = acc;
    }
    __syncthreads();
    float w1r[16], w2r[16];
    #pragma unroll
    for (int j = 0; j < 16; j++) { w1r[j] = wsh[j]; w2r[j] = wsh[16 + j]; }

    int base = blockIdx.x * (256 * SC_ILP) + t;
    int dd[SC_ILP], ss[SC_ILP], pos[SC_ILP];
    bool v[SC_ILP];
    #pragma unroll
    for (int j = 0; j < SC_ILP; j++) {
        int e = base + j * 256;
        v[j] = (e < EE);
        int ec = v[j] ? e : 0;
        dd[j] = dst[ec];
        ss[j] = src[ec];
    }
    #pragma unroll
    for (int j = 0; j < SC_ILP; j++)
        if (v[j]) pos[j] = atomicAdd(&cursor[dd[j]], 1);
    #pragma unroll
    for (int j = 0; j < SC_ILP; j++) {
        if (!v[j]) continue;
        int e = base + j * 256;
        const float4* rp = (const float4*)(ea + (size_t)e * DE);
        float4 q0 = rp[0], q1 = rp[1], q2 = rp[2], q3 = rp[3];
        float ev[16] = {q0.x, q0.y, q0.z, q0.w, q1.x, q1.y, q1.z, q1.w,
                        q2.x, q2.y, q2.z, q2.w, q3.x, q3.y, q3.z, q3.w};
        float e1 = 0.f, e2 = 0.f;
        #pragma unroll
        for (int k2 = 0; k2 < 16; k2++) {
            e1 += ev[k2] * w1r[k2];
            e2 += ev[k2] * w2r[k2];
        }
        recs[pos[j]] = make_int4(ss[j], e, __float_as_int(e1), __float_as_int(e2));
    }
}

// ---------------- per-layer: h = x@W, hs = h@a_s, hd = h@a_d
// W column in registers (64 VGPR/lane): __launch_bounds__(256,4) -> 128-VGPR budget.
template<int IN_BF16>
__global__ __launch_bounds__(256, 4) void k_gemm(const void* xin, const float* W,
                                                 const float* a_s, const float* a_d,
                                                 unsigned short* h, float* hs, float* hd) {
    int t = threadIdx.x, lane = t & 63;
    int wid0 = blockIdx.x * 4 + (t >> 6);        // 4096 waves total
    float Wcol[64];
    #pragma unroll
    for (int k = 0; k < 64; k++) Wcol[k] = W[k * 64 + lane];
    float asl = a_s[lane], adl = a_d[lane];
    for (int n0 = wid0; n0 < NN; n0 += 4096) {
        int n = __builtin_amdgcn_readfirstlane(n0);
        float acc = 0.f;
        if (IN_BF16) {
            const uint4* xr = (const uint4*)((const unsigned short*)xin + (size_t)n * 64);
            #pragma unroll
            for (int q = 0; q < 8; q++) {
                uint4 u = xr[q];
                unsigned uu[4] = {u.x, u.y, u.z, u.w};
                #pragma unroll
                for (int j = 0; j < 4; j++) {
                    acc += bf2f((unsigned short)(uu[j] & 0xFFFFu)) * Wcol[q * 8 + 2 * j];
                    acc += bf2f((unsigned short)(uu[j] >> 16))     * Wcol[q * 8 + 2 * j + 1];
                }
            }
        } else {
            const float4* xr = (const float4*)((const float*)xin + (size_t)n * 64);
            #pragma unroll
            for (int q = 0; q < 16; q++) {
                float4 u = xr[q];
                acc += u.x * Wcol[4 * q]     + u.y * Wcol[4 * q + 1]
                     + u.z * Wcol[4 * q + 2] + u.w * Wcol[4 * q + 3];
            }
        }
        h[(size_t)n * 64 + lane] = f2bf(acc);
        float ps = acc * asl, pd = acc * adl;
        #pragma unroll
        for (int off = 32; off; off >>= 1) {
            ps += __shfl_xor(ps, off);
            pd += __shfl_xor(pd, off);
        }
        if (lane == 0) { hs[n] = ps; hd[n] = pd; }
    }
}

// ---------------- fused per-node GAT.
// R12 = R2 structure (proven 112us) + distance-2 h prefetch in pass 2.
//  - pass 1 (lane=edge): one 16B rec gather carries {src,eid,ee1,ee2}; logit =
//    hs[src]+hd[d]+ee (short chain). ea row staged to LDS in parallel
//    (consumed only in pass 2); {att,src} -> arx.
//  - softmax: 1 exp/lane + two shuffle reductions; att written to LDS.
//  - pass 2: 4 edges/iter (16 lanes each, 4 ch/lane), ea+att from LDS,
//    h[src] global gather at prefetch DISTANCE 2 (two loads in flight;
//    d1 covered only ~60 of ~300cy L2 latency), paired-k v_pk_fma.
// deg>64 (P~1e-7) falls back to a recompute loop reading ee from the rec.
template<int L2>   // L2: selects ee field; fp32 output
__global__ __launch_bounds__(256, 3) void k_gat(const int4* __restrict__ recs,
                                                const int* __restrict__ offsets,
                                                const int* __restrict__ counts,
                                                const float* __restrict__ hs,
                                                const float* __restrict__ hd,
                                                const unsigned short* __restrict__ h,
                                                const float* __restrict__ ea,
                                                const float* __restrict__ We,
                                                const float* __restrict__ b,
                                                void* __restrict__ outv) {
    __shared__ float4 eal[4][4][64];   // [wave][k-quad][edge] : staged ea rows
    __shared__ float2 arx[4][64];      // [wave][edge] : {att, src-bits}
    int t = threadIdx.x, lane = t & 63, wv = t >> 6;
    int g = lane >> 4, cl = lane & 15;

    // W packed as k-pairs for the lane's 4 channels
    vf2 Wp[32];
    #pragma unroll
    for (int kp = 0; kp < 8; kp++) {
        float4 wa = *(const float4*)(We + (2 * kp) * 64 + 4 * cl);
        float4 wb = *(const float4*)(We + (2 * kp + 1) * 64 + 4 * cl);
        Wp[kp].x      = wa.x; Wp[kp].y      = wb.x;
        Wp[8 + kp].x  = wa.y; Wp[8 + kp].y  = wb.y;
        Wp[16 + kp].x = wa.z; Wp[16 + kp].y = wb.z;
        Wp[24 + kp].x = wa.w; Wp[24 + kp].y = wb.w;
    }

    int d = blockIdx.x * 4 + wv;           // grid is exactly NN/4
    int start = offsets[d];
    int deg = counts[d];

    if (deg == 0) {                        // isfinite -> 0, then bias + act
        if (g == 0) {
            float4 bl = *(const float4*)(b + 4 * cl);
            float o0 = (bl.x >= 0.f) ? bl.x : 0.01f * bl.x;
            float o1 = (bl.y >= 0.f) ? bl.y : 0.01f * bl.y;
            float o2 = (bl.z >= 0.f) ? bl.z : 0.01f * bl.z;
            float o3 = (bl.w >= 0.f) ? bl.w : 0.01f * bl.w;
            size_t oidx = (size_t)d * D + 4 * cl;
            if (L2) *(float4*)((float*)outv + oidx) = make_float4(o0, o1, o2, o3);
            else {
                ushort4 ov = {f2bf(o0), f2bf(o1), f2bf(o2), f2bf(o3)};
                *(ushort4*)((unsigned short*)outv + oidx) = ov;
            }
        }
        return;
    }

    float hdv = hd[d];
    bool fast = (deg <= 64);               // wave-uniform
    float m, invs;

    float ninf = -__builtin_inff();
    float a0 = ninf, a1 = ninf, a2 = ninf, a3 = ninf;

    if (fast) {
        // ---- pass 1: lane = edge; stage ea row + src; logit from rec's ee.
        float lg = ninf;
        if (lane < deg) {
            int4 r = recs[start + lane];
            const float4* ep = (const float4*)(ea + (size_t)r.y * DE);
            float4 q0 = ep[0], q1 = ep[1], q2 = ep[2], q3 = ep[3];
            float hsv = hs[r.x];
            eal[wv][0][lane] = q0; eal[wv][1][lane] = q1;
            eal[wv][2][lane] = q2; eal[wv][3][lane] = q3;
            arx[wv][lane].y = __int_as_float(r.x);
            float ee = __int_as_float(L2 ? r.w : r.z);
            lg = hsv + hdv + ee;
            lg = (lg >= 0.f) ? lg : 0.2f * lg;
        }

        // prologue h prefetch, distance 0 and 1 (needs only src; overlaps reductions)
        bool vC = (g < deg);
        int jC = vC ? g : 0;
        bool vN = (4 + g < deg);
        int jN = vN ? 4 + g : 0;
        int rxC = __float_as_int(arx[wv][jC].y);
        int rxN = __float_as_int(arx[wv][jN].y);
        ushort4 hvC = *(const ushort4*)(h + (size_t)rxC * D + 4 * cl);
        ushort4 hvN = *(const ushort4*)(h + (size_t)rxN * D + 4 * cl);

        // ---- softmax: max-reduce, one exp/lane, sum-reduce
        m = lg;
        #pragma unroll
        for (int off = 32; off; off >>= 1) m = fmaxf(m, __shfl_xor(m, off));
        float p = __expf(lg - m);          // lanes >= deg: lg=-inf -> p=0
        float s = p;
        #pragma unroll
        for (int off = 32; off; off >>= 1) s += __shfl_xor(s, off);
        invs = 1.0f / fmaxf(s, 1e-16f);
        if (lane < deg) arx[wv][lane].x = p * invs;   // final att into LDS

        float attC = arx[wv][jC].x;        // after the .x writes (same wave)
        float attN = arx[wv][jN].x;

        // ---- pass 2: 4 edges/iter; ea + att from LDS; h global prefetch d2.
        for (int i = 0; i < deg; i += 4) {
            int jnn = i + 8 + g;
            bool vNN = (jnn < deg);
            int jNN = vNN ? jnn : 0;
            float2 arNN = arx[wv][jNN];
            int rxNN = __float_as_int(arNN.y);
            ushort4 hvNN = *(const ushort4*)(h + (size_t)rxNN * D + 4 * cl);

            vf2 acA = {0.f, 0.f}, acB = {0.f, 0.f}, acC2 = {0.f, 0.f}, acD = {0.f, 0.f};
            #pragma unroll
            for (int kq = 0; kq < 4; kq++) {
                float4 q = eal[wv][kq][jC];
                vf2 eA; eA.x = q.x; eA.y = q.y;      // k-pair 2kq (packed from load)
                vf2 eB; eB.x = q.z; eB.y = q.w;      // k-pair 2kq+1
                acA += eA * Wp[2 * kq];       acA += eB * Wp[2 * kq + 1];
                acB += eA * Wp[8 + 2 * kq];   acB += eB * Wp[8 + 2 * kq + 1];
                acC2 += eA * Wp[16 + 2 * kq]; acC2 += eB * Wp[16 + 2 * kq + 1];
                acD += eA * Wp[24 + 2 * kq];  acD += eB * Wp[24 + 2 * kq + 1];
            }
            float e0 = acA.x + acA.y, e1 = acB.x + acB.y;
            float e2 = acC2.x + acC2.y, e3 = acD.x + acD.y;
            float o0 = (bf2f(hvC.x) + e0) * attC;
            float o1 = (bf2f(hvC.y) + e1) * attC;
            float o2 = (bf2f(hvC.z) + e2) * attC;
            float o3 = (bf2f(hvC.w) + e3) * attC;
            if (vC) {
                a0 = fmaxf(a0, o0); a1 = fmaxf(a1, o1);
                a2 = fmaxf(a2, o2); a3 = fmaxf(a3, o3);
            }
            // rotate 2-deep pipeline
            jC = jN; vC = vN; hvC = hvN; attC = attN;
            jN = jNN; vN = vNN; hvN = hvNN; attN = arNN.x;
        }
    } else {
        // ---- slow path (deg > 64): online softmax + recompute loop (ee from rec)
        float mm = ninf, s = 0.f;
        for (int i = lane; i < deg; i += 64) {
            int4 r = recs[start + i];
            float ee = __int_as_float(L2 ? r.w : r.z);
            float lg = hs[r.x] + hdv + ee;
            lg = (lg >= 0.f) ? lg : 0.2f * lg;
            float mn = fmaxf(mm, lg);
            s = ((mm == mn) ? s : s * __expf(mm - mn)) + __expf(lg - mn);
            mm = mn;
        }
        #pragma unroll
        for (int off = 32; off; off >>= 1) {
            float m2 = __shfl_xor(mm, off);
            float s2 = __shfl_xor(s, off);
            float mn = fmaxf(mm, m2);
            float sa = (mm == mn) ? s : s * __expf(mm - mn);
            float sb = (m2 == mn) ? s2 : s2 * __expf(m2 - mn);
            s = sa + sb;
            mm = mn;
        }
        m = mm;
        invs = 1.0f / fmaxf(s, 1e-16f);

        for (int i = 0; i < deg; i += 4) {
            int j = i + g;
            bool valid = (j < deg);
            int jc = valid ? j : 0;
            int4 r = recs[start + jc];
            float ee = __int_as_float(L2 ? r.w : r.z);
            float lg = hs[r.x] + hdv + ee;
            lg = (lg >= 0.f) ? lg : 0.2f * lg;
            float att = __expf(lg - m) * invs;
            const float4* ep = (const float4*)(ea + (size_t)r.y * DE);
            float4 q0 = ep[0], q1 = ep[1], q2 = ep[2], q3 = ep[3];
            ushort4 hv = *(const ushort4*)(h + (size_t)r.x * D + 4 * cl);
            float4 qs[4] = {q0, q1, q2, q3};
            vf2 acA = {0.f, 0.f}, acB = {0.f, 0.f}, acC2 = {0.f, 0.f}, acD = {0.f, 0.f};
            #pragma unroll
            for (int kq = 0; kq < 4; kq++) {
                float4 q = qs[kq];
                vf2 eA; eA.x = q.x; eA.y = q.y;
                vf2 eB; eB.x = q.z; eB.y = q.w;
                acA += eA * Wp[2 * kq];       acA += eB * Wp[2 * kq + 1];
                acB += eA * Wp[8 + 2 * kq];   acB += eB * Wp[8 + 2 * kq + 1];
                acC2 += eA * Wp[16 + 2 * kq]; acC2 += eB * Wp[16 + 2 * kq + 1];
                acD += eA * Wp[24 + 2 * kq];  acD += eB * Wp[24 + 2 * kq + 1];
            }
            float e0 = acA.x + acA.y, e1 = acB.x + acB.y;
            float e2 = acC2.x + acC2.y, e3 = acD.x + acD.y;
            float o0 = (bf2f(hv.x) + e0) * att;
            float o1 = (bf2f(hv.y) + e1) * att;
            float o2 = (bf2f(hv.z) + e2) * att;
            float o3 = (bf2f(hv.w) + e3) * att;
            if (valid) {
                a0 = fmaxf(a0, o0); a1 = fmaxf(a1, o1);
                a2 = fmaxf(a2, o2); a3 = fmaxf(a3, o3);
            }
        }
    }

    // combine the 4 groups (xor lanes 16, 32)
    #pragma unroll
    for (int off = 16; off <= 32; off <<= 1) {
        a0 = fmaxf(a0, __shfl_xor(a0, off));
        a1 = fmaxf(a1, __shfl_xor(a1, off));
        a2 = fmaxf(a2, __shfl_xor(a2, off));
        a3 = fmaxf(a3, __shfl_xor(a3, off));
    }

    if (g == 0) {
        float4 bl = *(const float4*)(b + 4 * cl);
        float o0 = a0 + bl.x, o1 = a1 + bl.y;
        float o2 = a2 + bl.z, o3 = a3 + bl.w;
        o0 = (o0 >= 0.f) ? o0 : 0.01f * o0;
        o1 = (o1 >= 0.f) ? o1 : 0.01f * o1;
        o2 = (o2 >= 0.f) ? o2 : 0.01f * o2;
        o3 = (o3 >= 0.f) ? o3 : 0.01f * o3;
        size_t oidx = (size_t)d * D + 4 * cl;
        if (L2) {
            *(float4*)((float*)outv + oidx) = make_float4(o0, o1, o2, o3);
        } else {
            ushort4 ov = {f2bf(o0), f2bf(o1), f2bf(o2), f2bf(o3)};
            *(ushort4*)((unsigned short*)outv + oidx) = ov;
        }
    }
}

extern "C" void kernel_launch(void* const* d_in, const int* in_sizes, int n_in,
                              void* d_out, int out_size, void* d_ws, size_t ws_size,
                              hipStream_t stream) {
    const float* X   = (const float*)d_in[0];
    const int*   eix = (const int*)d_in[1];
    const float* ea  = (const float*)d_in[2];
    const float* W1  = (const float*)d_in[3];
    const float* We1 = (const float*)d_in[4];
    const float* as1 = (const float*)d_in[5];
    const float* ad1 = (const float*)d_in[6];
    const float* ae1 = (const float*)d_in[7];
    const float* b1  = (const float*)d_in[8];
    const float* W2  = (const float*)d_in[9];
    const float* We2 = (const float*)d_in[10];
    const float* as2 = (const float*)d_in[11];
    const float* ad2 = (const float*)d_in[12];
    const float* ae2 = (const float*)d_in[13];
    const float* b2  = (const float*)d_in[14];

    const int* src = eix;
    const int* dst = eix + EE;

    // workspace carve — total ~39.4 MB
    char* w = (char*)d_ws;
    int4* recs = (int4*)w;               w += (size_t)EE * 16;         // 25.6 MB
    unsigned short* hA = (unsigned short*)w; w += (size_t)NN * D * 2;  // 6.4 MB (h1)
    unsigned short* hB = (unsigned short*)w; w += (size_t)NN * D * 2;  // 6.4 MB (c1 -> h2 in-place)
    float* hs = (float*)w;               w += (size_t)NN * 4;
    float* hd = (float*)w;               w += (size_t)NN * 4;
    int* counts = (int*)w;               w += (size_t)NN * 4;
    int* offsets = (int*)w;              w += (size_t)NN * 4;
    int* cursor = (int*)w;               w += (size_t)NN * 4;
    int* bsum = (int*)w;                 w += 256 * 4;

    const int nchunks = (NN + 255) / 256;   // 196
    const int nhblk = (EE + 256 * HI_ILP - 1) / (256 * HI_ILP);   // 1563
    const int nsblk = (EE + 256 * SC_ILP - 1) / (256 * SC_ILP);   // 782

    hipMemsetAsync(counts, 0, (size_t)NN * 4, stream);
    k_hist<<<nhblk, 256, 0, stream>>>(dst, counts);
    k_scanA<<<nchunks, 256, 0, stream>>>(counts, bsum);
    k_scanB<<<1, 256, 0, stream>>>(bsum, nchunks);
    k_scanC<<<nchunks, 256, 0, stream>>>(counts, bsum, offsets, cursor);
    k_scatter<<<nsblk, 256, 0, stream>>>(src, dst, ea, We1, ae1, We2, ae2, cursor, recs);

    // layer 1
    k_gemm<0><<<1024, 256, 0, stream>>>(X, W1, as1, ad1, hA, hs, hd);
    k_gat<0><<<NN / 4, 256, 0, stream>>>(recs, offsets, counts, hs, hd, hA, ea, We1, b1, hB);
    // layer 2
    k_gemm<1><<<1024, 256, 0, stream>>>(hB, W2, as2, ad2, hB, hs, hd);   // in-place
    k_gat<1><<<NN / 4, 256, 0, stream>>>(recs, offsets, counts, hs, hd, hB, ea, We2, b2,
                                         (float*)d_out);
}

// Round 7
// 565.515 us; speedup vs baseline: 1.1091x; 1.1091x over previous
//
#include <hip/hip_runtime.h>
#include <cstdint>
#include <cstddef>

#define NN 50000
#define EE 1600000
#define D  64
#define DE 16

typedef __attribute__((ext_vector_type(2))) float vf2;

__device__ __forceinline__ float bf2f(unsigned short u) {
    return __uint_as_float(((unsigned)u) << 16);
}
__device__ __forceinline__ unsigned short f2bf(float f) {
    unsigned u = __float_as_uint(f);
    unsigned r = u + 0x7FFFu + ((u >> 16) & 1u);   // RNE
    return (unsigned short)(r >> 16);
}

// ---------------- histogram of dst (4-edge ILP -> 4 atomic chains in flight)
#define HI_ILP 4
__global__ __launch_bounds__(256) void k_hist(const int* __restrict__ dst,
                                              int* __restrict__ counts) {
    int base = blockIdx.x * (256 * HI_ILP) + threadIdx.x;
    int dd[HI_ILP]; bool v[HI_ILP];
    #pragma unroll
    for (int j = 0; j < HI_ILP; j++) {
        int e = base + j * 256;
        v[j] = (e < EE);
        dd[j] = dst[v[j] ? e : 0];
    }
    #pragma unroll
    for (int j = 0; j < HI_ILP; j++)
        if (v[j]) atomicAdd(&counts[dd[j]], 1);
}

// ---------------- scan stage A: per-256-chunk sums
__global__ __launch_bounds__(256) void k_scanA(const int* counts, int* bsum) {
    __shared__ int tmp[256];
    int t = threadIdx.x, i = blockIdx.x * 256 + t;
    tmp[t] = (i < NN) ? counts[i] : 0;
    __syncthreads();
    for (int off = 128; off; off >>= 1) {
        if (t < off) tmp[t] += tmp[t + off];
        __syncthreads();
    }
    if (t == 0) bsum[blockIdx.x] = tmp[0];
}

// ---------------- scan stage C (merged with old stage B): each block re-scans
// the 196 raw block sums in LDS (cheap) to get its own exclusive base, then
// does the local exclusive scan of counts. One dispatch saved.
__global__ __launch_bounds__(256) void k_scanC(const int* counts, const int* bsum,
                                               int nchunks, int* offsets, int* cursor) {
    __shared__ int tmpb[256];
    __shared__ int tmp[256];
    int t = threadIdx.x;
    // scan of bsum (raw per-chunk sums) to derive this block's exclusive base
    int bv = (t < nchunks) ? bsum[t] : 0;
    tmpb[t] = bv; __syncthreads();
    for (int off = 1; off < 256; off <<= 1) {
        int x = (t >= off) ? tmpb[t - off] : 0;
        __syncthreads();
        tmpb[t] += x;
        __syncthreads();
    }
    int base = (blockIdx.x > 0) ? tmpb[blockIdx.x - 1] : 0;   // broadcast read

    int i = blockIdx.x * 256 + t;
    int v = (i < NN) ? counts[i] : 0;
    tmp[t] = v; __syncthreads();
    for (int off = 1; off < 256; off <<= 1) {
        int x = (t >= off) ? tmp[t - off] : 0;
        __syncthreads();
        tmp[t] += x;
        __syncthreads();
    }
    int excl = tmp[t] - v + base;
    if (i < NN) { offsets[i] = excl; cursor[i] = excl; }
}

// ---------------- fused: layer-1 GEMM (blocks 0..1023, W staged in LDS so the
// kernel keeps DEFAULT launch bounds) + edge scatter (blocks >= 1024, ILP-2 at
// 3125 blocks -> full occupancy; R6's ILP-8/782-block version was TLP-starved
// at 28% occupancy -> 133us). GEMM is VALU/LDS-bound, scatter latency-bound
// with 2% VALU: near-perfect co-residents, and one dispatch gap is saved.
#define SC_ILP 2
__global__ __launch_bounds__(256) void k_scatter_gemm(
        const int* __restrict__ src, const int* __restrict__ dst,
        const float* __restrict__ ea,
        const float* __restrict__ We1, const float* __restrict__ ae1,
        const float* __restrict__ We2, const float* __restrict__ ae2,
        int* __restrict__ cursor, int4* __restrict__ recs,
        const float* __restrict__ X, const float* __restrict__ W,
        const float* __restrict__ a_s, const float* __restrict__ a_d,
        unsigned short* __restrict__ h, float* __restrict__ hs,
        float* __restrict__ hd) {
    __shared__ float sh[64 * 64];          // gemm: W staged; scatter: first 32 = wae
    int t = threadIdx.x;

    if (blockIdx.x < 1024) {
        // ---- layer-1 GEMM, W in LDS. sh[k*64+lane] read: lanes 0..63 hit
        // banks 0..31 twice (2-way, free per m136).
        for (int i = t; i < 1024; i += 256)
            ((float4*)sh)[i] = ((const float4*)W)[i];
        __syncthreads();
        int lane = t & 63;
        int wid0 = blockIdx.x * 4 + (t >> 6);        // 4096 waves
        float asl = a_s[lane], adl = a_d[lane];
        for (int n0 = wid0; n0 < NN; n0 += 4096) {
            int n = __builtin_amdgcn_readfirstlane(n0);
            const float4* xr = (const float4*)(X + (size_t)n * 64);
            float acc = 0.f;
            #pragma unroll
            for (int q = 0; q < 16; q++) {
                float4 u = xr[q];
                acc += u.x * sh[(4 * q) * 64 + lane]
                     + u.y * sh[(4 * q + 1) * 64 + lane]
                     + u.z * sh[(4 * q + 2) * 64 + lane]
                     + u.w * sh[(4 * q + 3) * 64 + lane];
            }
            h[(size_t)n * 64 + lane] = f2bf(acc);
            float ps = acc * asl, pd = acc * adl;
            #pragma unroll
            for (int off = 32; off; off >>= 1) {
                ps += __shfl_xor(ps, off);
                pd += __shfl_xor(pd, off);
            }
            if (lane == 0) { hs[n] = ps; hd[n] = pd; }
        }
        return;
    }

    // ---- scatter: {src, eid, ee1, ee2} records, ee precomputed here (keeps
    // gat pass-1's logit path to one 16B rec gather).
    if (t < 32) {
        const float* We = (t < 16) ? We1 : We2;
        const float* ae = (t < 16) ? ae1 : ae2;
        int k = t & 15;
        float acc = 0.f;
        #pragma unroll
        for (int c = 0; c < 64; c++) acc += We[k * 64 + c] * ae[c];
        sh[t] = acc;
    }
    __syncthreads();
    float w1r[16], w2r[16];
    #pragma unroll
    for (int j = 0; j < 16; j++) { w1r[j] = sh[j]; w2r[j] = sh[16 + j]; }

    int base = (blockIdx.x - 1024) * (256 * SC_ILP) + t;
    int dd[SC_ILP], ss[SC_ILP], pos[SC_ILP];
    bool v[SC_ILP];
    #pragma unroll
    for (int j = 0; j < SC_ILP; j++) {
        int e = base + j * 256;
        v[j] = (e < EE);
        int ec = v[j] ? e : 0;
        dd[j] = dst[ec];
        ss[j] = src[ec];
    }
    #pragma unroll
    for (int j = 0; j < SC_ILP; j++)
        if (v[j]) pos[j] = atomicAdd(&cursor[dd[j]], 1);
    #pragma unroll
    for (int j = 0; j < SC_ILP; j++) {
        if (!v[j]) continue;
        int e = base + j * 256;
        const float4* rp = (const float4*)(ea + (size_t)e * DE);
        float4 q0 = rp[0], q1 = rp[1], q2 = rp[2], q3 = rp[3];
        float ev[16] = {q0.x, q0.y, q0.z, q0.w, q1.x, q1.y, q1.z, q1.w,
                        q2.x, q2.y, q2.z, q2.w, q3.x, q3.y, q3.z, q3.w};
        float e1 = 0.f, e2 = 0.f;
        #pragma unroll
        for (int k2 = 0; k2 < 16; k2++) {
            e1 += ev[k2] * w1r[k2];
            e2 += ev[k2] * w2r[k2];
        }
        recs[pos[j]] = make_int4(ss[j], e, __float_as_int(e1), __float_as_int(e2));
    }
}

// ---------------- standalone layer-2 GEMM (register Wcol, (256,4))
template<int IN_BF16>
__global__ __launch_bounds__(256, 4) void k_gemm(const void* xin, const float* W,
                                                 const float* a_s, const float* a_d,
                                                 unsigned short* h, float* hs, float* hd) {
    int t = threadIdx.x, lane = t & 63;
    int wid0 = blockIdx.x * 4 + (t >> 6);        // 4096 waves total
    float Wcol[64];
    #pragma unroll
    for (int k = 0; k < 64; k++) Wcol[k] = W[k * 64 + lane];
    float asl = a_s[lane], adl = a_d[lane];
    for (int n0 = wid0; n0 < NN; n0 += 4096) {
        int n = __builtin_amdgcn_readfirstlane(n0);
        float acc = 0.f;
        if (IN_BF16) {
            const uint4* xr = (const uint4*)((const unsigned short*)xin + (size_t)n * 64);
            #pragma unroll
            for (int q = 0; q < 8; q++) {
                uint4 u = xr[q];
                unsigned uu[4] = {u.x, u.y, u.z, u.w};
                #pragma unroll
                for (int j = 0; j < 4; j++) {
                    acc += bf2f((unsigned short)(uu[j] & 0xFFFFu)) * Wcol[q * 8 + 2 * j];
                    acc += bf2f((unsigned short)(uu[j] >> 16))     * Wcol[q * 8 + 2 * j + 1];
                }
            }
        } else {
            const float4* xr = (const float4*)((const float*)xin + (size_t)n * 64);
            #pragma unroll
            for (int q = 0; q < 16; q++) {
                float4 u = xr[q];
                acc += u.x * Wcol[4 * q]     + u.y * Wcol[4 * q + 1]
                     + u.z * Wcol[4 * q + 2] + u.w * Wcol[4 * q + 3];
            }
        }
        h[(size_t)n * 64 + lane] = f2bf(acc);
        float ps = acc * asl, pd = acc * adl;
        #pragma unroll
        for (int off = 32; off; off >>= 1) {
            ps += __shfl_xor(ps, off);
            pd += __shfl_xor(pd, off);
        }
        if (lane == 0) { hs[n] = ps; hd[n] = pd; }
    }
}

// ---------------- fused per-node GAT (R12 structure, kept).
//  - pass 1 (lane=edge): one 16B rec gather carries {src,eid,ee1,ee2}; logit =
//    hs[src]+hd[d]+ee (short chain). ea row staged to LDS in parallel
//    (consumed only in pass 2); {att,src} -> arx.
//  - softmax: 1 exp/lane + two shuffle reductions; att written to LDS.
//  - pass 2: 4 edges/iter (16 lanes each, 4 ch/lane), ea+att from LDS,
//    h[src] global gather at prefetch distance 2, paired-k v_pk_fma.
// deg>64 (P~1e-7) falls back to a recompute loop reading ee from the rec.
template<int L2>   // L2: selects ee field; fp32 output
__global__ __launch_bounds__(256, 3) void k_gat(const int4* __restrict__ recs,
                                                const int* __restrict__ offsets,
                                                const int* __restrict__ counts,
                                                const float* __restrict__ hs,
                                                const float* __restrict__ hd,
                                                const unsigned short* __restrict__ h,
                                                const float* __restrict__ ea,
                                                const float* __restrict__ We,
                                                const float* __restrict__ b,
                                                void* __restrict__ outv) {
    __shared__ float4 eal[4][4][64];   // [wave][k-quad][edge] : staged ea rows
    __shared__ float2 arx[4][64];      // [wave][edge] : {att, src-bits}
    int t = threadIdx.x, lane = t & 63, wv = t >> 6;
    int g = lane >> 4, cl = lane & 15;

    // W packed as k-pairs for the lane's 4 channels
    vf2 Wp[32];
    #pragma unroll
    for (int kp = 0; kp < 8; kp++) {
        float4 wa = *(const float4*)(We + (2 * kp) * 64 + 4 * cl);
        float4 wb = *(const float4*)(We + (2 * kp + 1) * 64 + 4 * cl);
        Wp[kp].x      = wa.x; Wp[kp].y      = wb.x;
        Wp[8 + kp].x  = wa.y; Wp[8 + kp].y  = wb.y;
        Wp[16 + kp].x = wa.z; Wp[16 + kp].y = wb.z;
        Wp[24 + kp].x = wa.w; Wp[24 + kp].y = wb.w;
    }

    int d = blockIdx.x * 4 + wv;           // grid is exactly NN/4
    int start = offsets[d];
    int deg = counts[d];

    if (deg == 0) {                        // isfinite -> 0, then bias + act
        if (g == 0) {
            float4 bl = *(const float4*)(b + 4 * cl);
            float o0 = (bl.x >= 0.f) ? bl.x : 0.01f * bl.x;
            float o1 = (bl.y >= 0.f) ? bl.y : 0.01f * bl.y;
            float o2 = (bl.z >= 0.f) ? bl.z : 0.01f * bl.z;
            float o3 = (bl.w >= 0.f) ? bl.w : 0.01f * bl.w;
            size_t oidx = (size_t)d * D + 4 * cl;
            if (L2) *(float4*)((float*)outv + oidx) = make_float4(o0, o1, o2, o3);
            else {
                ushort4 ov = {f2bf(o0), f2bf(o1), f2bf(o2), f2bf(o3)};
                *(ushort4*)((unsigned short*)outv + oidx) = ov;
            }
        }
        return;
    }

    float hdv = hd[d];
    bool fast = (deg <= 64);               // wave-uniform
    float m, invs;

    float ninf = -__builtin_inff();
    float a0 = ninf, a1 = ninf, a2 = ninf, a3 = ninf;

    if (fast) {
        // ---- pass 1: lane = edge; stage ea row + src; logit from rec's ee.
        float lg = ninf;
        if (lane < deg) {
            int4 r = recs[start + lane];
            const float4* ep = (const float4*)(ea + (size_t)r.y * DE);
            float4 q0 = ep[0], q1 = ep[1], q2 = ep[2], q3 = ep[3];
            float hsv = hs[r.x];
            eal[wv][0][lane] = q0; eal[wv][1][lane] = q1;
            eal[wv][2][lane] = q2; eal[wv][3][lane] = q3;
            arx[wv][lane].y = __int_as_float(r.x);
            float ee = __int_as_float(L2 ? r.w : r.z);
            lg = hsv + hdv + ee;
            lg = (lg >= 0.f) ? lg : 0.2f * lg;
        }

        // prologue h prefetch, distance 0 and 1 (needs only src; overlaps reductions)
        bool vC = (g < deg);
        int jC = vC ? g : 0;
        bool vN = (4 + g < deg);
        int jN = vN ? 4 + g : 0;
        int rxC = __float_as_int(arx[wv][jC].y);
        int rxN = __float_as_int(arx[wv][jN].y);
        ushort4 hvC = *(const ushort4*)(h + (size_t)rxC * D + 4 * cl);
        ushort4 hvN = *(const ushort4*)(h + (size_t)rxN * D + 4 * cl);

        // ---- softmax: max-reduce, one exp/lane, sum-reduce
        m = lg;
        #pragma unroll
        for (int off = 32; off; off >>= 1) m = fmaxf(m, __shfl_xor(m, off));
        float p = __expf(lg - m);          // lanes >= deg: lg=-inf -> p=0
        float s = p;
        #pragma unroll
        for (int off = 32; off; off >>= 1) s += __shfl_xor(s, off);
        invs = 1.0f / fmaxf(s, 1e-16f);
        if (lane < deg) arx[wv][lane].x = p * invs;   // final att into LDS

        float attC = arx[wv][jC].x;        // after the .x writes (same wave)
        float attN = arx[wv][jN].x;

        // ---- pass 2: 4 edges/iter; ea + att from LDS; h global prefetch d2.
        for (int i = 0; i < deg; i += 4) {
            int jnn = i + 8 + g;
            bool vNN = (jnn < deg);
            int jNN = vNN ? jnn : 0;
            float2 arNN = arx[wv][jNN];
            int rxNN = __float_as_int(arNN.y);
            ushort4 hvNN = *(const ushort4*)(h + (size_t)rxNN * D + 4 * cl);

            vf2 acA = {0.f, 0.f}, acB = {0.f, 0.f}, acC2 = {0.f, 0.f}, acD = {0.f, 0.f};
            #pragma unroll
            for (int kq = 0; kq < 4; kq++) {
                float4 q = eal[wv][kq][jC];
                vf2 eA; eA.x = q.x; eA.y = q.y;      // k-pair 2kq (packed from load)
                vf2 eB; eB.x = q.z; eB.y = q.w;      // k-pair 2kq+1
                acA += eA * Wp[2 * kq];       acA += eB * Wp[2 * kq + 1];
                acB += eA * Wp[8 + 2 * kq];   acB += eB * Wp[8 + 2 * kq + 1];
                acC2 += eA * Wp[16 + 2 * kq]; acC2 += eB * Wp[16 + 2 * kq + 1];
                acD += eA * Wp[24 + 2 * kq];  acD += eB * Wp[24 + 2 * kq + 1];
            }
            float e0 = acA.x + acA.y, e1 = acB.x + acB.y;
            float e2 = acC2.x + acC2.y, e3 = acD.x + acD.y;
            float o0 = (bf2f(hvC.x) + e0) * attC;
            float o1 = (bf2f(hvC.y) + e1) * attC;
            float o2 = (bf2f(hvC.z) + e2) * attC;
            float o3 = (bf2f(hvC.w) + e3) * attC;
            if (vC) {
                a0 = fmaxf(a0, o0); a1 = fmaxf(a1, o1);
                a2 = fmaxf(a2, o2); a3 = fmaxf(a3, o3);
            }
            // rotate 2-deep pipeline
            jC = jN; vC = vN; hvC = hvN; attC = attN;
            jN = jNN; vN = vNN; hvN = hvNN; attN = arNN.x;
        }
    } else {
        // ---- slow path (deg > 64): online softmax + recompute loop (ee from rec)
        float mm = ninf, s = 0.f;
        for (int i = lane; i < deg; i += 64) {
            int4 r = recs[start + i];
            float ee = __int_as_float(L2 ? r.w : r.z);
            float lg = hs[r.x] + hdv + ee;
            lg = (lg >= 0.f) ? lg : 0.2f * lg;
            float mn = fmaxf(mm, lg);
            s = ((mm == mn) ? s : s * __expf(mm - mn)) + __expf(lg - mn);
            mm = mn;
        }
        #pragma unroll
        for (int off = 32; off; off >>= 1) {
            float m2 = __shfl_xor(mm, off);
            float s2 = __shfl_xor(s, off);
            float mn = fmaxf(mm, m2);
            float sa = (mm == mn) ? s : s * __expf(mm - mn);
            float sb = (m2 == mn) ? s2 : s2 * __expf(m2 - mn);
            s = sa + sb;
            mm = mn;
        }
        m = mm;
        invs = 1.0f / fmaxf(s, 1e-16f);

        for (int i = 0; i < deg; i += 4) {
            int j = i + g;
            bool valid = (j < deg);
            int jc = valid ? j : 0;
            int4 r = recs[start + jc];
            float ee = __int_as_float(L2 ? r.w : r.z);
            float lg = hs[r.x] + hdv + ee;
            lg = (lg >= 0.f) ? lg : 0.2f * lg;
            float att = __expf(lg - m) * invs;
            const float4* ep = (const float4*)(ea + (size_t)r.y * DE);
            float4 q0 = ep[0], q1 = ep[1], q2 = ep[2], q3 = ep[3];
            ushort4 hv = *(const ushort4*)(h + (size_t)r.x * D + 4 * cl);
            float4 qs[4] = {q0, q1, q2, q3};
            vf2 acA = {0.f, 0.f}, acB = {0.f, 0.f}, acC2 = {0.f, 0.f}, acD = {0.f, 0.f};
            #pragma unroll
            for (int kq = 0; kq < 4; kq++) {
                float4 q = qs[kq];
                vf2 eA; eA.x = q.x; eA.y = q.y;
                vf2 eB; eB.x = q.z; eB.y = q.w;
                acA += eA * Wp[2 * kq];       acA += eB * Wp[2 * kq + 1];
                acB += eA * Wp[8 + 2 * kq];   acB += eB * Wp[8 + 2 * kq + 1];
                acC2 += eA * Wp[16 + 2 * kq]; acC2 += eB * Wp[16 + 2 * kq + 1];
                acD += eA * Wp[24 + 2 * kq];  acD += eB * Wp[24 + 2 * kq + 1];
            }
            float e0 = acA.x + acA.y, e1 = acB.x + acB.y;
            float e2 = acC2.x + acC2.y, e3 = acD.x + acD.y;
            float o0 = (bf2f(hv.x) + e0) * att;
            float o1 = (bf2f(hv.y) + e1) * att;
            float o2 = (bf2f(hv.z) + e2) * att;
            float o3 = (bf2f(hv.w) + e3) * att;
            if (valid) {
                a0 = fmaxf(a0, o0); a1 = fmaxf(a1, o1);
                a2 = fmaxf(a2, o2); a3 = fmaxf(a3, o3);
            }
        }
    }

    // combine the 4 groups (xor lanes 16, 32)
    #pragma unroll
    for (int off = 16; off <= 32; off <<= 1) {
        a0 = fmaxf(a0, __shfl_xor(a0, off));
        a1 = fmaxf(a1, __shfl_xor(a1, off));
        a2 = fmaxf(a2, __shfl_xor(a2, off));
        a3 = fmaxf(a3, __shfl_xor(a3, off));
    }

    if (g == 0) {
        float4 bl = *(const float4*)(b + 4 * cl);
        float o0 = a0 + bl.x, o1 = a1 + bl.y;
        float o2 = a2 + bl.z, o3 = a3 + bl.w;
        o0 = (o0 >= 0.f) ? o0 : 0.01f * o0;
        o1 = (o1 >= 0.f) ? o1 : 0.01f * o1;
        o2 = (o2 >= 0.f) ? o2 : 0.01f * o2;
        o3 = (o3 >= 0.f) ? o3 : 0.01f * o3;
        size_t oidx = (size_t)d * D + 4 * cl;
        if (L2) {
            *(float4*)((float*)outv + oidx) = make_float4(o0, o1, o2, o3);
        } else {
            ushort4 ov = {f2bf(o0), f2bf(o1), f2bf(o2), f2bf(o3)};
            *(ushort4*)((unsigned short*)outv + oidx) = ov;
        }
    }
}

extern "C" void kernel_launch(void* const* d_in, const int* in_sizes, int n_in,
                              void* d_out, int out_size, void* d_ws, size_t ws_size,
                              hipStream_t stream) {
    const float* X   = (const float*)d_in[0];
    const int*   eix = (const int*)d_in[1];
    const float* ea  = (const float*)d_in[2];
    const float* W1  = (const float*)d_in[3];
    const float* We1 = (const float*)d_in[4];
    const float* as1 = (const float*)d_in[5];
    const float* ad1 = (const float*)d_in[6];
    const float* ae1 = (const float*)d_in[7];
    const float* b1  = (const float*)d_in[8];
    const float* W2  = (const float*)d_in[9];
    const float* We2 = (const float*)d_in[10];
    const float* as2 = (const float*)d_in[11];
    const float* ad2 = (const float*)d_in[12];
    const float* ae2 = (const float*)d_in[13];
    const float* b2  = (const float*)d_in[14];

    const int* src = eix;
    const int* dst = eix + EE;

    // workspace carve — total ~39.4 MB
    char* w = (char*)d_ws;
    int4* recs = (int4*)w;               w += (size_t)EE * 16;         // 25.6 MB
    unsigned short* hA = (unsigned short*)w; w += (size_t)NN * D * 2;  // 6.4 MB (h1)
    unsigned short* hB = (unsigned short*)w; w += (size_t)NN * D * 2;  // 6.4 MB (c1 -> h2 in-place)
    float* hs = (float*)w;               w += (size_t)NN * 4;
    float* hd = (float*)w;               w += (size_t)NN * 4;
    int* counts = (int*)w;               w += (size_t)NN * 4;
    int* offsets = (int*)w;              w += (size_t)NN * 4;
    int* cursor = (int*)w;               w += (size_t)NN * 4;
    int* bsum = (int*)w;                 w += 256 * 4;

    const int nchunks = (NN + 255) / 256;   // 196
    const int nhblk = (EE + 256 * HI_ILP - 1) / (256 * HI_ILP);   // 1563
    const int nsblk = (EE + 256 * SC_ILP - 1) / (256 * SC_ILP);   // 3125

    hipMemsetAsync(counts, 0, (size_t)NN * 4, stream);
    k_hist<<<nhblk, 256, 0, stream>>>(dst, counts);
    k_scanA<<<nchunks, 256, 0, stream>>>(counts, bsum);
    k_scanC<<<nchunks, 256, 0, stream>>>(counts, bsum, nchunks, offsets, cursor);

    // fused: layer-1 GEMM (1024 blocks, LDS-W) + scatter (3125 blocks, ILP-2)
    k_scatter_gemm<<<1024 + nsblk, 256, 0, stream>>>(src, dst, ea,
                                                     We1, ae1, We2, ae2,
                                                     cursor, recs,
                                                     X, W1, as1, ad1, hA, hs, hd);
    k_gat<0><<<NN / 4, 256, 0, stream>>>(recs, offsets, counts, hs, hd, hA, ea, We1, b1, hB);
    // layer 2
    k_gemm<1><<<1024, 256, 0, stream>>>(hB, W2, as2, ad2, hB, hs, hd);   // in-place
    k_gat<1><<<NN / 4, 256, 0, stream>>>(recs, offsets, counts, hs, hd, hB, ea, We2, b2,
                                         (float*)d_out);
}